// Round 8
// baseline (217.298 us; speedup 1.0000x reference)
//
#include <hip/hip_runtime.h>
#include <math.h>

// Problem constants (fixed by setup_inputs): N=65536 rows, D=512, out = 1 float.
#define NROWS 65536
#define DIM   512

__device__ __forceinline__ unsigned bucket_of(float r) {
    // r in [0,1); mult by 2^16 is exact (exponent shift) -> monotone bucketing.
    unsigned b = (unsigned)(r * 65536.0f);
    return b > 65535u ? 65535u : b;
}

__device__ __forceinline__ float dot4(float4 a, float4 b) {
    return a.x * b.x + a.y * b.y + a.z * b.z + a.w * b.w;
}

// --- prep: b-norms (block 0) + ranking histogram (blocks 1..256) ------------
__global__ __launch_bounds__(256) void k_prep(const float* __restrict__ rk,
                                              const float* __restrict__ b2,
                                              const float* __restrict__ b3,
                                              unsigned* __restrict__ hist,
                                              float* __restrict__ bn) {
    if (blockIdx.x == 0) {
        if (threadIdx.x < 64) {
            const int lane = threadIdx.x;
            const float4* b2v = (const float4*)b2;
            const float4* b3v = (const float4*)b3;
            const float4 u0 = b2v[lane], u1 = b2v[lane + 64];
            const float4 w0 = b3v[lane], w1 = b3v[lane + 64];
            float s2 = dot4(u0, u0) + dot4(u1, u1);
            float s3 = dot4(w0, w0) + dot4(w1, w1);
#pragma unroll
            for (int o = 32; o > 0; o >>= 1) {
                s2 += __shfl_xor(s2, o);
                s3 += __shfl_xor(s3, o);
            }
            if (lane == 0) { bn[0] = sqrtf(s2); bn[1] = sqrtf(s3); }
        }
    } else {
        const int i = (int)((blockIdx.x - 1) * 256u + threadIdx.x);
        atomicAdd(&hist[bucket_of(rk[i])], 1u);
    }
}

// --- exclusive scan of histogram (merged block-sum + scan) ------------------
// Block b: redundantly sums all bins below its slice (L2-hot, coalesced),
// then scans its own 256 bins. Writes exclusive start of each bin.
__global__ __launch_bounds__(256) void k_histscan(const unsigned* __restrict__ hist,
                                                  unsigned* __restrict__ histScan) {
    const int t = threadIdx.x, lane = t & 63, wid = t >> 6;
    const int b = (int)blockIdx.x;
    __shared__ unsigned base_s[4], w[4];
    unsigned pre = 0;
    const int lim = b * 256;
#pragma unroll 4
    for (int i = t; i < lim; i += 256) pre += hist[i];
#pragma unroll
    for (int o = 32; o > 0; o >>= 1) pre += __shfl_xor(pre, o);
    if (lane == 0) base_s[wid] = pre;
    const unsigned h = hist[lim + t];
    unsigned inc = h;
#pragma unroll
    for (int o = 1; o < 64; o <<= 1) {
        unsigned n = __shfl_up(inc, o);
        if (lane >= o) inc += n;
    }
    if (lane == 63) w[wid] = inc;
    __syncthreads();
    unsigned base = base_s[0] + base_s[1] + base_s[2] + base_s[3];
    for (int k = 0; k < wid; ++k) base += w[k];
    histScan[lim + t] = base + inc - h;  // exclusive start of bin
}

// --- per-row cosine sims + direct scatter of packed records -----------------
// Row per wave, low VGPR (8 waves/SIMD). Slot reserved via atomicAdd on
// histScan: afterwards histScan[b] = end_b, so start_b = histScan[b-1].
__global__ __launch_bounds__(256) void k_rows(
    const float* __restrict__ x, const float* __restrict__ b2,
    const float* __restrict__ b3, const float* __restrict__ rk,
    const float* __restrict__ bn, unsigned* __restrict__ histScan,
    float4* __restrict__ sq)
{
    const int row  = (int)((blockIdx.x * 256u + threadIdx.x) >> 6);
    const int lane = threadIdx.x & 63;
    const float4* xr  = (const float4*)(x + (size_t)row * DIM);
    const float4* b2v = (const float4*)b2;
    const float4* b3v = (const float4*)b3;
    const float4 xv0 = xr[lane], xv1 = xr[lane + 64];
    const float4 u0 = b2v[lane], u1 = b2v[lane + 64];
    const float4 w0 = b3v[lane], w1 = b3v[lane + 64];
    float d2 = dot4(xv0, u0) + dot4(xv1, u1);
    float d3 = dot4(xv0, w0) + dot4(xv1, w1);
    float ss = dot4(xv0, xv0) + dot4(xv1, xv1);
#pragma unroll
    for (int o = 32; o > 0; o >>= 1) {
        d2 += __shfl_xor(d2, o);
        d3 += __shfl_xor(d3, o);
        ss += __shfl_xor(ss, o);
    }
    if (lane == 0) {
        const float nx = sqrtf(ss);
        const float e2v = expf(d2 / fmaxf(nx * bn[0], 1e-8f));
        const float e3v = expf(d3 / fmaxf(nx * bn[1], 1e-8f));
        const float r = rk[row];
        const unsigned b = bucket_of(r);
        const unsigned slot = atomicAdd(&histScan[b], 1u);
        sq[slot] = make_float4(r, __int_as_float(row), e2v, e3v);
    }
}

// --- exact rank within bucket, scatter into sorted order + chunk sums -------
// Ranks are a near-identity permutation (|rank - slot| < max bucket size),
// so chunk sums accumulate in 5 LDS cells (chunks bid-2..bid+2) with a
// global-atomic fallback for (practically impossible) strays.
// Tie-break: higher original index first (reversed stable descending argsort).
__global__ __launch_bounds__(256) void k_rank(const float4* __restrict__ sq,
                                              const unsigned* __restrict__ histScan,
                                              float2* __restrict__ se,
                                              float* __restrict__ chunk2,
                                              float* __restrict__ chunk3,
                                              float* __restrict__ out) {
    __shared__ float c2s[5], c3s[5];
    const int t = threadIdx.x;
    if (t < 5) { c2s[t] = 0.f; c3s[t] = 0.f; }
    __syncthreads();
    const int s = (int)(blockIdx.x * 256u + t);
    const float4 me = sq[s];
    const float r = me.x;
    const int   i = __float_as_int(me.y);
    const unsigned b = bucket_of(r);
    const unsigned start = b ? histScan[b - 1] : 0u;
    const unsigned end   = histScan[b];
    unsigned rank = start;
    for (unsigned m = start; m < end; ++m) {
        const float4 o = sq[m];
        const float rj = o.x;
        const int   j  = __float_as_int(o.y);
        if (rj < r || (rj == r && j > i)) rank++;
    }
    se[rank] = make_float2(me.z, me.w);
    const int rel = (int)(rank >> 8) - ((int)blockIdx.x - 2);
    if (rel >= 0 && rel < 5) {
        atomicAdd(&c2s[rel], me.z);
        atomicAdd(&c3s[rel], me.w);
    } else {
        atomicAdd(&chunk2[rank >> 8], me.z);
        atomicAdd(&chunk3[rank >> 8], me.w);
    }
    __syncthreads();
    if (t < 5) {
        const int cc = (int)blockIdx.x - 2 + t;
        if (cc >= 0 && cc < 256) {
            if (c2s[t] != 0.f) atomicAdd(&chunk2[cc], c2s[t]);
            if (c3s[t] != 0.f) atomicAdd(&chunk3[cc], c3s[t]);
        }
    }
    if (s == 0) out[0] = 0.f;  // d_out poisoned each call; k_logsum runs after
}

// --- final: per-block scan + logf + atomic; block computes its own base by --
// reducing the chunk sums below it; block 255 adds (N-1)*log(total).
__global__ __launch_bounds__(256) void k_logsum(const float2* __restrict__ se,
                                                const float* __restrict__ chunk2,
                                                const float* __restrict__ chunk3,
                                                float* __restrict__ out) {
    __shared__ float lt2s[4], lt3s[4], all2s[4], all3s[4], w2[4], w3[4];
    __shared__ double dsum[4];
    const int t    = threadIdx.x;
    const int lane = t & 63;
    const int wid  = t >> 6;
    const int b    = (int)blockIdx.x;
    const int g    = b * 256 + t;
    // chunk-sum prefixes (exclusive of own chunk) and totals
    const float c2 = chunk2[t];
    const float c3 = chunk3[t];
    float lt2 = (t < b) ? c2 : 0.f, lt3 = (t < b) ? c3 : 0.f;
    float al2 = c2, al3 = c3;
#pragma unroll
    for (int o = 32; o > 0; o >>= 1) {
        lt2 += __shfl_xor(lt2, o);
        lt3 += __shfl_xor(lt3, o);
        al2 += __shfl_xor(al2, o);
        al3 += __shfl_xor(al3, o);
    }
    if (lane == 0) { lt2s[wid] = lt2; lt3s[wid] = lt3; all2s[wid] = al2; all3s[wid] = al3; }
    // inclusive wave scan of this block's 256 sorted values
    const float2 v = se[g];
    float p2 = v.x;
    float p3 = v.y;
#pragma unroll
    for (int o = 1; o < 64; o <<= 1) {
        float n2 = __shfl_up(p2, o);
        float n3 = __shfl_up(p3, o);
        if (lane >= o) { p2 += n2; p3 += n3; }
    }
    if (lane == 63) { w2[wid] = p2; w3[wid] = p3; }
    __syncthreads();
    float base2 = lt2s[0] + lt2s[1] + lt2s[2] + lt2s[3];
    float base3 = lt3s[0] + lt3s[1] + lt3s[2] + lt3s[3];
    for (int w = 0; w < wid; ++w) { base2 += w2[w]; base3 += w3[w]; }
    double term = 0.0;
    if (g < NROWS - 1) {  // prefix lengths 1..N-1 only
        term = (double)logf(base2 + p2) + (double)logf(base3 + p3);
    }
#pragma unroll
    for (int o = 32; o > 0; o >>= 1) term += __shfl_down(term, o);
    if (lane == 0) dsum[wid] = term;
    __syncthreads();
    if (t == 0) {
        double contrib = -(dsum[0] + dsum[1] + dsum[2] + dsum[3]);
        if (b == 255) {
            const float T2 = all2s[0] + all2s[1] + all2s[2] + all2s[3];
            const float T3 = all3s[0] + all3s[1] + all3s[2] + all3s[3];
            contrib += (double)(NROWS - 1) * ((double)logf(T2) + (double)logf(T3));
        }
        atomicAdd(out, (float)contrib);
    }
}

extern "C" void kernel_launch(void* const* d_in, const int* in_sizes, int n_in,
                              void* d_out, int out_size, void* d_ws, size_t ws_size,
                              hipStream_t stream) {
    const float* x  = (const float*)d_in[0];  // [N, D]
    const float* b2 = (const float*)d_in[1];  // [1, D]
    const float* b3 = (const float*)d_in[2];  // [1, D]
    const float* rk = (const float*)d_in[3];  // [N]

    // Workspace layout (4-byte units). Zeroed region first: hist + chunks.
    unsigned* hist     = (unsigned*)d_ws;            // N  (zeroed)
    float*    chunk2   = (float*)(hist + NROWS);     // 256 (zeroed)
    float*    chunk3   = chunk2 + 256;               // 256 (zeroed)
    unsigned* histScan = (unsigned*)(chunk3 + 256);  // N
    float4*   sq   = (float4*)(histScan + NROWS);    // 4N (16B-aligned offset)
    float2*   se   = (float2*)(sq + NROWS);          // 2N
    float*    bn   = (float*)(se + NROWS);           // 2

    // hist + chunk sums must be zero each call (ws poisoned 0xAA).
    hipMemsetAsync(hist, 0, (NROWS + 512) * sizeof(unsigned), stream);

    k_prep<<<257, 256, 0, stream>>>(rk, b2, b3, hist, bn);
    k_histscan<<<256, 256, 0, stream>>>(hist, histScan);
    k_rows<<<NROWS / 4, 256, 0, stream>>>(x, b2, b3, rk, bn, histScan, sq);
    k_rank<<<NROWS / 256, 256, 0, stream>>>(sq, histScan, se, chunk2, chunk3,
                                            (float*)d_out);
    k_logsum<<<NROWS / 256, 256, 0, stream>>>(se, chunk2, chunk3, (float*)d_out);
}

// Round 9
// 211.118 us; speedup vs baseline: 1.0293x; 1.0293x over previous
//
#include <hip/hip_runtime.h>
#include <math.h>

// Problem constants (fixed by setup_inputs): N=65536 rows, D=512, out = 1 float.
#define NROWS 65536
#define DIM   512

__device__ __forceinline__ unsigned bucket_of(float r) {
    // r in [0,1); mult by 2^16 is exact (exponent shift) -> monotone bucketing.
    unsigned b = (unsigned)(r * 65536.0f);
    return b > 65535u ? 65535u : b;
}

// --- per-row cosine sims -> e2/e3, fused b-norms + ranking histogram --------
__global__ __launch_bounds__(256) void k_rows(
    const float* __restrict__ x, const float* __restrict__ b2,
    const float* __restrict__ b3, const float* __restrict__ ranking,
    float* __restrict__ e2, float* __restrict__ e3,
    unsigned* __restrict__ hist)
{
    const int row  = (int)((blockIdx.x * 256u + threadIdx.x) >> 6);  // wave per row
    const int lane = threadIdx.x & 63;
    const float4* xr  = (const float4*)(x + (size_t)row * DIM);
    const float4* b2v = (const float4*)b2;
    const float4* b3v = (const float4*)b3;
    float dot2 = 0.f, dot3 = 0.f, ss = 0.f, sb2 = 0.f, sb3 = 0.f;
#pragma unroll
    for (int k = 0; k < 2; ++k) {
        const int idx = lane + (k << 6);   // 128 float4 per row
        const float4 xv = xr[idx];
        const float4 u  = b2v[idx];
        const float4 w  = b3v[idx];
        dot2 += xv.x * u.x + xv.y * u.y + xv.z * u.z + xv.w * u.w;
        dot3 += xv.x * w.x + xv.y * w.y + xv.z * w.z + xv.w * w.w;
        ss   += xv.x * xv.x + xv.y * xv.y + xv.z * xv.z + xv.w * xv.w;
        sb2  += u.x * u.x + u.y * u.y + u.z * u.z + u.w * u.w;
        sb3  += w.x * w.x + w.y * w.y + w.z * w.z + w.w * w.w;
    }
#pragma unroll
    for (int off = 32; off > 0; off >>= 1) {
        dot2 += __shfl_xor(dot2, off);
        dot3 += __shfl_xor(dot3, off);
        ss   += __shfl_xor(ss, off);
        sb2  += __shfl_xor(sb2, off);
        sb3  += __shfl_xor(sb3, off);
    }
    if (lane == 0) {
        const float nx = sqrtf(ss);
        const float s2 = dot2 / fmaxf(nx * sqrtf(sb2), 1e-8f);
        const float s3 = dot3 / fmaxf(nx * sqrtf(sb3), 1e-8f);
        e2[row] = expf(s2);
        e3[row] = expf(s3);
        atomicAdd(&hist[bucket_of(ranking[row])], 1u);
    }
}

// --- per-block (256-bin) sums of histogram, coalesced -----------------------
__global__ __launch_bounds__(256) void k_bsum(const unsigned* __restrict__ hist,
                                              unsigned* __restrict__ bsum) {
    const int t = threadIdx.x;
    unsigned v = hist[blockIdx.x * 256u + t];
#pragma unroll
    for (int o = 32; o > 0; o >>= 1) v += __shfl_xor(v, o);
    __shared__ unsigned a[4];
    if ((t & 63) == 0) a[t >> 6] = v;
    __syncthreads();
    if (t == 0) bsum[blockIdx.x] = a[0] + a[1] + a[2] + a[3];
}

// --- exclusive scan of histogram: block b scans its 256 bins + redundant ----
// reduction of the <=256 block partials below it (L2-hot, trivial).
__global__ __launch_bounds__(256) void k_histscan(const unsigned* __restrict__ hist,
                                                  const unsigned* __restrict__ bsum,
                                                  unsigned* __restrict__ histScan) {
    const int t = threadIdx.x, lane = t & 63, wid = t >> 6;
    const int b = (int)blockIdx.x;
    __shared__ unsigned base_s[4], w[4];
    unsigned pre = (t < b) ? bsum[t] : 0u;
#pragma unroll
    for (int o = 32; o > 0; o >>= 1) pre += __shfl_xor(pre, o);
    if (lane == 0) base_s[wid] = pre;
    const unsigned h = hist[b * 256u + t];
    unsigned inc = h;
#pragma unroll
    for (int o = 1; o < 64; o <<= 1) {
        unsigned n = __shfl_up(inc, o);
        if (lane >= o) inc += n;
    }
    if (lane == 63) w[wid] = inc;
    __syncthreads();
    unsigned base = base_s[0] + base_s[1] + base_s[2] + base_s[3];
    for (int k = 0; k < wid; ++k) base += w[k];
    histScan[b * 256u + t] = base + inc - h;  // exclusive start of bin
}

// --- scatter packed (r, idx, e2, e3) records into bucket slots --------------
// Reserves via atomicAdd on histScan itself: afterwards histScan[b] = end_b.
__global__ __launch_bounds__(256) void k_scatter(const float* __restrict__ ranking,
                                                 const float* __restrict__ e2,
                                                 const float* __restrict__ e3,
                                                 unsigned* __restrict__ histScan,
                                                 float4* __restrict__ sq) {
    const int i = (int)(blockIdx.x * 256u + threadIdx.x);
    const float r = ranking[i];
    const unsigned b = bucket_of(r);
    const unsigned slot = atomicAdd(&histScan[b], 1u);
    sq[slot] = make_float4(r, __int_as_float(i), e2[i], e3[i]);
}

// --- exact rank within bucket (packed records), scatter e into sorted order -
// Post-scatter histScan[b] = end_b; start_b = histScan[b-1] (0 for b==0).
// Tie-break: higher original index first (matches reversed stable descending argsort).
__global__ __launch_bounds__(256) void k_rank(const float4* __restrict__ sq,
                                              const unsigned* __restrict__ histScan,
                                              float* __restrict__ se2,
                                              float* __restrict__ se3) {
    const int s = (int)(blockIdx.x * 256u + threadIdx.x);
    const float4 me = sq[s];
    const float r = me.x;
    const int   i = __float_as_int(me.y);
    const unsigned b = bucket_of(r);
    const unsigned start = b ? histScan[b - 1] : 0u;
    const unsigned end   = histScan[b];
    unsigned rank = start;
    for (unsigned m = start; m < end; ++m) {
        const float4 o = sq[m];
        const float rj = o.x;
        const int   j  = __float_as_int(o.y);
        if (rj < r || (rj == r && j > i)) rank++;
    }
    se2[rank] = me.z;
    se3[rank] = me.w;
}

// --- per-chunk (256-elem) sums of sorted e; also zero-init out --------------
__global__ __launch_bounds__(256) void k_chunksum(const float* __restrict__ se2,
                                                  const float* __restrict__ se3,
                                                  float* __restrict__ chunk2,
                                                  float* __restrict__ chunk3,
                                                  float* __restrict__ out) {
    __shared__ float a2[4], a3[4];
    const int t = threadIdx.x;
    const int g = (int)(blockIdx.x * 256u + t);
    float v2 = se2[g];
    float v3 = se3[g];
#pragma unroll
    for (int o = 32; o > 0; o >>= 1) {
        v2 += __shfl_down(v2, o);
        v3 += __shfl_down(v3, o);
    }
    const int lane = t & 63, wid = t >> 6;
    if (lane == 0) { a2[wid] = v2; a3[wid] = v3; }
    __syncthreads();
    if (t == 0) {
        chunk2[blockIdx.x] = a2[0] + a2[1] + a2[2] + a2[3];
        chunk3[blockIdx.x] = a3[0] + a3[1] + a3[2] + a3[3];
        if (blockIdx.x == 0) out[0] = 0.f;  // d_out is poisoned each call
    }
}

// --- final: per-block scan + logf + atomic; block computes its own base by --
// reducing the chunk sums below it; block 255 adds (N-1)*log(total).
__global__ __launch_bounds__(256) void k_logsum(const float* __restrict__ se2,
                                                const float* __restrict__ se3,
                                                const float* __restrict__ chunk2,
                                                const float* __restrict__ chunk3,
                                                float* __restrict__ out) {
    __shared__ float lt2s[4], lt3s[4], all2s[4], all3s[4], w2[4], w3[4];
    __shared__ double dsum[4];
    const int t    = threadIdx.x;
    const int lane = t & 63;
    const int wid  = t >> 6;
    const int b    = (int)blockIdx.x;
    const int g    = b * 256 + t;
    // chunk-sum prefixes (exclusive of own chunk) and totals
    const float c2 = chunk2[t];
    const float c3 = chunk3[t];
    float lt2 = (t < b) ? c2 : 0.f, lt3 = (t < b) ? c3 : 0.f;
    float al2 = c2, al3 = c3;
#pragma unroll
    for (int o = 32; o > 0; o >>= 1) {
        lt2 += __shfl_xor(lt2, o);
        lt3 += __shfl_xor(lt3, o);
        al2 += __shfl_xor(al2, o);
        al3 += __shfl_xor(al3, o);
    }
    if (lane == 0) { lt2s[wid] = lt2; lt3s[wid] = lt3; all2s[wid] = al2; all3s[wid] = al3; }
    // inclusive wave scan of this block's 256 sorted values
    float p2 = se2[g];
    float p3 = se3[g];
#pragma unroll
    for (int o = 1; o < 64; o <<= 1) {
        float n2 = __shfl_up(p2, o);
        float n3 = __shfl_up(p3, o);
        if (lane >= o) { p2 += n2; p3 += n3; }
    }
    if (lane == 63) { w2[wid] = p2; w3[wid] = p3; }
    __syncthreads();
    float base2 = lt2s[0] + lt2s[1] + lt2s[2] + lt2s[3];
    float base3 = lt3s[0] + lt3s[1] + lt3s[2] + lt3s[3];
    for (int w = 0; w < wid; ++w) { base2 += w2[w]; base3 += w3[w]; }
    double term = 0.0;
    if (g < NROWS - 1) {  // prefix lengths 1..N-1 only
        term = (double)logf(base2 + p2) + (double)logf(base3 + p3);
    }
#pragma unroll
    for (int o = 32; o > 0; o >>= 1) term += __shfl_down(term, o);
    if (lane == 0) dsum[wid] = term;
    __syncthreads();
    if (t == 0) {
        double contrib = -(dsum[0] + dsum[1] + dsum[2] + dsum[3]);
        if (b == 255) {
            const float T2 = all2s[0] + all2s[1] + all2s[2] + all2s[3];
            const float T3 = all3s[0] + all3s[1] + all3s[2] + all3s[3];
            contrib += (double)(NROWS - 1) * ((double)logf(T2) + (double)logf(T3));
        }
        atomicAdd(out, (float)contrib);
    }
}

extern "C" void kernel_launch(void* const* d_in, const int* in_sizes, int n_in,
                              void* d_out, int out_size, void* d_ws, size_t ws_size,
                              hipStream_t stream) {
    const float* x  = (const float*)d_in[0];  // [N, D]
    const float* b2 = (const float*)d_in[1];  // [1, D]
    const float* b3 = (const float*)d_in[2];  // [1, D]
    const float* rk = (const float*)d_in[3];  // [N]

    // Workspace layout (4-byte units).
    unsigned* hist     = (unsigned*)d_ws;            // N (must be zeroed)
    unsigned* histScan = hist + NROWS;               // N
    float4*   sq   = (float4*)(histScan + NROWS);    // 4N (offset 512KB, 16B-aligned)
    float*    e2   = (float*)(sq + NROWS);           // N
    float*    e3   = e2 + NROWS;                     // N
    float*    se2  = e3 + NROWS;                     // N
    float*    se3  = se2 + NROWS;                    // N
    float*    chunk2 = se3 + NROWS;                  // 256
    float*    chunk3 = chunk2 + 256;                 // 256
    unsigned* bsum   = (unsigned*)(chunk3 + 256);    // 256

    // hist must be zero each call (ws poisoned 0xAA).
    hipMemsetAsync(hist, 0, NROWS * sizeof(unsigned), stream);

    k_rows<<<NROWS / 4, 256, 0, stream>>>(x, b2, b3, rk, e2, e3, hist);
    k_bsum<<<256, 256, 0, stream>>>(hist, bsum);
    k_histscan<<<256, 256, 0, stream>>>(hist, bsum, histScan);
    k_scatter<<<NROWS / 256, 256, 0, stream>>>(rk, e2, e3, histScan, sq);
    k_rank<<<NROWS / 256, 256, 0, stream>>>(sq, histScan, se2, se3);
    k_chunksum<<<NROWS / 256, 256, 0, stream>>>(se2, se3, chunk2, chunk3, (float*)d_out);
    k_logsum<<<NROWS / 256, 256, 0, stream>>>(se2, se3, chunk2, chunk3, (float*)d_out);
}